// Round 17
// baseline (264.844 us; speedup 1.0000x reference)
//
#include <hip/hip_runtime.h>

// Problem constants
#define NQ 20
#define DIMQ (1 << NQ)          // 2^20
#define NB 16                   // BATCH
#define NT 4                    // N_TERMS
#define RBITS 15                // low bits untouched by gates
#define NCOL (1 << (RBITS + 4)) // 2^15 r-values * 16 batches = 524288 columns
#define TILES 2                 // column-tiles per block (grid-stride)
#define NBLK (NCOL / 128 / TILES) // 2048 blocks = 8 per CU, one generation

// U table layout in ws/LDS: per (k,b): 36 floats (16 complex interleaved + 4 pad)
//   base = (k*16 + b) * 36 ; entry (i,j): re at base + (i*4+j)*2, im at +1
//   36 floats = 144 B = 9*16 B -> every (k,b) base is 16B-aligned.
#define USTRIDE 36
#define UTOT (64 * USTRIDE)     // 2304 floats = 9216 B

// lane <-> lane^1 exchange as DPP quad_perm [1,0,3,2] (0xB1): pure VALU.
__device__ __forceinline__ float dpp_swap1(float x) {
  int r = __builtin_amdgcn_mov_dpp(__builtin_bit_cast(int, x), 0xB1, 0xF, 0xF, true);
  return __builtin_bit_cast(float, r);
}

// Complex MAC via packed-FP32 VOP3P: o += u * s  (u=(ur,ui), s=(sr,si)).
__device__ __forceinline__ void cfma(float2& o, const float2 u, const float2 s) {
  asm("v_pk_fma_f32 %0, %1, %2, %0 op_sel_hi:[0,1,1]\n\t"
      "v_pk_fma_f32 %0, %1, %2, %0 op_sel:[1,1,0] op_sel_hi:[1,0,1] neg_lo:[1,0,0]"
      : "+v"(o) : "v"(u), "v"(s));
}
// o = u * s (no accumulate); early-clobber since %0 is written before last read.
__device__ __forceinline__ float2 cmul(const float2 u, const float2 s) {
  float2 o;
  asm("v_pk_mul_f32 %0, %1, %2 op_sel_hi:[0,1]\n\t"
      "v_pk_fma_f32 %0, %1, %2, %0 op_sel:[1,1,0] op_sel_hi:[1,0,1] neg_lo:[1,0,0]"
      : "=&v"(o) : "v"(u), "v"(s));
  return o;
}

// ---------------------------------------------------------------------------
// Kernel A: U[k,b] = exp(-i * H_k * t_{k,b}),  H_k = 0.5*(A + A^H), A = Hr + i Hi
// 256 threads: 64 tasks (k,b) x 4 rows. Scaling (2^-4) + 8-term Taylor +
// 4 squarings (trunc error ~1e-10, invisible at fp32 / 2.1e-4 threshold).
// ---------------------------------------------------------------------------
__global__ __launch_bounds__(256) void compute_u_kernel(
    const float* __restrict__ Hre, const float* __restrict__ Him,
    const float* __restrict__ tevo, float* __restrict__ uout) {
  __shared__ float er_s[64][4][4];
  __shared__ float ei_s[64][4][4];

  const int tid  = threadIdx.x;   // 0..255
  const int task = tid >> 2;      // 0..63
  const int row  = tid & 3;       // 0..3
  const int k    = task >> 4;     // 0..3
  const int b    = task & 15;     // 0..15

  float Ar[4][4], Ai[4][4];
#pragma unroll
  for (int i = 0; i < 4; i++) {
#pragma unroll
    for (int j = 0; j < 4; j++) {
      Ar[i][j] = Hre[k * 16 + i * 4 + j];
      Ai[i][j] = Him[k * 16 + i * 4 + j];
    }
  }
  const float t = tevo[k * NB + b];
  const float ts = t * (1.0f / 16.0f);  // scale 2^-4 folded in

  // G = -i * H * ts ; H = 0.5*(A + A^H)
  float Gr[4][4], Gi[4][4];
#pragma unroll
  for (int i = 0; i < 4; i++) {
#pragma unroll
    for (int j = 0; j < 4; j++) {
      const float hr = 0.5f * (Ar[i][j] + Ar[j][i]);
      const float hi = 0.5f * (Ai[i][j] - Ai[j][i]);
      Gr[i][j] = ts * hi;
      Gi[i][j] = -ts * hr;
    }
  }

  // Taylor: E = I + sum_{m=1..8} G^m/m!   (row `row` only; full G in regs)
  float Er[4], Ei[4], Tr[4], Ti[4];
#pragma unroll
  for (int j = 0; j < 4; j++) {
    Er[j] = (j == row) ? 1.0f : 0.0f;
    Ei[j] = 0.0f;
    Tr[j] = Er[j];
    Ti[j] = 0.0f;
  }
#pragma unroll
  for (int m = 1; m <= 8; m++) {
    const float inv = 1.0f / (float)m;
    float nr[4], ni[4];
#pragma unroll
    for (int j = 0; j < 4; j++) {
      float ar = 0.0f, ai = 0.0f;
#pragma unroll
      for (int p = 0; p < 4; p++) {
        ar += Tr[p] * Gr[p][j] - Ti[p] * Gi[p][j];
        ai += Tr[p] * Gi[p][j] + Ti[p] * Gr[p][j];
      }
      nr[j] = ar * inv;
      ni[j] = ai * inv;
    }
#pragma unroll
    for (int j = 0; j < 4; j++) {
      Tr[j] = nr[j]; Ti[j] = ni[j];
      Er[j] += nr[j]; Ei[j] += ni[j];
    }
  }

  // 4 squarings via LDS (uniform trip count -> barriers are safe)
  for (int q = 0; q < 4; q++) {
    __syncthreads();
#pragma unroll
    for (int j = 0; j < 4; j++) {
      er_s[task][row][j] = Er[j];
      ei_s[task][row][j] = Ei[j];
    }
    __syncthreads();
    float nr[4], ni[4];
#pragma unroll
    for (int j = 0; j < 4; j++) {
      float ar = 0.0f, ai = 0.0f;
#pragma unroll
      for (int p = 0; p < 4; p++) {
        ar += Er[p] * er_s[task][p][j] - Ei[p] * ei_s[task][p][j];
        ai += Er[p] * ei_s[task][p][j] + Ei[p] * er_s[task][p][j];
      }
      nr[j] = ar; ni[j] = ai;
    }
#pragma unroll
    for (int j = 0; j < 4; j++) { Er[j] = nr[j]; Ei[j] = ni[j]; }
  }

  // Store U rows: layout [k][b][16 complex interleaved], row stride 36 floats
  const int ubase = (k * 16 + b) * USTRIDE;
#pragma unroll
  for (int j = 0; j < 4; j++) {
    uout[ubase + (row * 4 + j) * 2]     = Er[j];
    uout[ubase + (row * 4 + j) * 2 + 1] = Ei[j];
  }
}

// ---------------------------------------------------------------------------
// Kernel B (r14 compute core + 2-tile grid-stride):
// two ADJACENT LANES per column (r,b); each owns one 16-g half.
// Block stages the 9 KiB U table ONCE (block-shared + one barrier), then
// loops over TILES=2 column-tiles of 128 cols. Grid = 2048 blocks = exactly
// 8 blocks/CU (one dispatch generation): per-block cold-start (U stage +
// first HBM load latency) is amortized over 2 tiles, and tile-1 loads issue
// while tile-0 NT stores drain (cross-iteration pipelining).
// Gates k=1..3 half-local; k=0 cross term via DPP quad_perm; all complex
// MACs are 2x v_pk_fma_f32.
// ---------------------------------------------------------------------------
__global__ __launch_bounds__(256, 8) void apply_gates_kernel(
    const float* __restrict__ sre, const float* __restrict__ sim,
    const float* __restrict__ u, float* __restrict__ out) {
  __shared__ __align__(16) float ul[UTOT];          // 9216 B block-shared
  const int tid   = threadIdx.x;
  const int half  = tid & 1;                        // lanes alternate halves
  const int lcol  = tid >> 1;                       // 0..127 within tile
  const int b     = lcol & 15;
  const int gbase = half << 4;

  // stage U table once (9 KiB; UTOT = 9*256 exactly)
#pragma unroll
  for (int q = 0; q < 9; q++) ul[tid + q * 256] = u[tid + q * 256];
  __syncthreads();

  const float* ub0 = &ul[b * USTRIDE];   // k = 0 block
  const int h4 = half * 4;               // float offset of (j=2h) entry pair

  for (int t = 0; t < TILES; t++) {
    const int col = (blockIdx.x * TILES + t) * 128 + lcol;  // r*16 + b

    // own half: 16 complex -- one burst of 32 dword loads
    float2 s[16];
#pragma unroll
    for (int q = 0; q < 16; q++) {
      const int off = col + ((gbase + q) << 19);
      s[q].x = sre[off];
      s[q].y = sim[off];
    }

    float2 o[16];

    // ---- k = 0 (g bits [4:3]) : own term + DPP-exchanged cross term ----
    // own output g = half<<4 | b3<<3 | l : row i = 2*half + b3.
    // own sources s[l] (j=2*half), s[8+l] (j=2*half+1).
    // cross partial: my sources' contribution to partner output with row
    // i' = 2*(half^1) + b3; partner adds the DPP-swapped value.
#pragma unroll
    for (int b3 = 0; b3 < 2; b3++) {
      const float4 vo = *(const float4*)(ub0 + (half * 2 + b3) * 8 + h4);
      const float4 vc = *(const float4*)(ub0 + ((half ^ 1) * 2 + b3) * 8 + h4);
      const float2 vo0 = make_float2(vo.x, vo.y), vo1 = make_float2(vo.z, vo.w);
      const float2 vc0 = make_float2(vc.x, vc.y), vc1 = make_float2(vc.z, vc.w);
#pragma unroll
      for (int ll = 0; ll < 8; ll++) {
        const int gq = b3 * 8 + ll;
        o[gq] = cmul(vo0, s[ll]);
        cfma(o[gq], vo1, s[8 + ll]);
        float2 p = cmul(vc0, s[ll]);
        cfma(p, vc1, s[8 + ll]);
        o[gq].x += dpp_swap1(p.x);
        o[gq].y += dpp_swap1(p.y);
      }
    }

    // ---- k = 1..3: fully local to the half (bits [3:0] of g) ----
#pragma unroll
    for (int k = 1; k < 4; k++) {
      const int sh = 3 - k;  // 2, 1, 0
      const float* ub = &ul[(k * 16 + b) * USTRIDE];
#pragma unroll
      for (int i = 0; i < 4; i++) {
        const float4 v0 = *(const float4*)(ub + i * 8);      // j=0,1
        const float4 v1 = *(const float4*)(ub + i * 8 + 4);  // j=2,3
        const float2 u0 = make_float2(v0.x, v0.y), u1 = make_float2(v0.z, v0.w);
        const float2 u2 = make_float2(v1.x, v1.y), u3 = make_float2(v1.z, v1.w);
#pragma unroll
        for (int qq = 0; qq < 4; qq++) {
          const int low  = qq & ((1 << sh) - 1);
          const int high = (qq >> sh) << (sh + 2);
          const int gb   = high | low;           // gq with pair bits cleared
          const int gq   = gb | (i << sh);
          cfma(o[gq], u0, s[gb]);
          cfma(o[gq], u1, s[gb | (1 << sh)]);
          cfma(o[gq], u2, s[gb | (2 << sh)]);
          cfma(o[gq], u3, s[gb | (3 << sh)]);
        }
      }
    }

#pragma unroll
    for (int q = 0; q < 16; q++) {
      const int off = col + ((gbase + q) << 19);
      __builtin_nontemporal_store(o[q].x, out + off);               // real
      __builtin_nontemporal_store(o[q].y, out + off + (1 << 24));   // imag
    }
  }
}

extern "C" void kernel_launch(void* const* d_in, const int* in_sizes, int n_in,
                              void* d_out, int out_size, void* d_ws, size_t ws_size,
                              hipStream_t stream) {
  const float* Hre  = (const float*)d_in[0];
  const float* Him  = (const float*)d_in[1];
  const float* tevo = (const float*)d_in[2];
  const float* sre  = (const float*)d_in[3];
  const float* sim  = (const float*)d_in[4];
  float* out = (float*)d_out;
  float* uws = (float*)d_ws;  // UTOT floats = 9216 B

  compute_u_kernel<<<1, 256, 0, stream>>>(Hre, Him, tevo, uws);
  apply_gates_kernel<<<NBLK, 256, 0, stream>>>(sre, sim, uws, out);
}

// Round 18
// 60.496 us; speedup vs baseline: 4.3779x; 4.3779x over previous
//
#include <hip/hip_runtime.h>

// Problem constants
#define NQ 20
#define DIMQ (1 << NQ)          // 2^20
#define NB 16                   // BATCH
#define NT 4                    // N_TERMS
#define RBITS 15                // low bits untouched by gates
#define NCOL (1 << (RBITS + 4)) // 2^15 r-values * 16 batches = 524288 columns
#define TILES 2                 // column-tiles per block (grid-stride)
#define NBLK (NCOL / 128 / TILES) // 2048 blocks

// U table layout in ws/LDS: per (k,b): 36 floats (16 complex interleaved + 4 pad)
//   base = (k*16 + b) * 36 ; entry (i,j): re at base + (i*4+j)*2, im at +1
//   36 floats = 144 B = 9*16 B -> every (k,b) base is 16B-aligned.
#define USTRIDE 36
#define UTOT (64 * USTRIDE)     // 2304 floats = 9216 B

// lane <-> lane^1 exchange as DPP quad_perm [1,0,3,2] (0xB1): pure VALU.
__device__ __forceinline__ float dpp_swap1(float x) {
  int r = __builtin_amdgcn_mov_dpp(__builtin_bit_cast(int, x), 0xB1, 0xF, 0xF, true);
  return __builtin_bit_cast(float, r);
}

// Complex MAC via packed-FP32 VOP3P: o += u * s  (u=(ur,ui), s=(sr,si)).
__device__ __forceinline__ void cfma(float2& o, const float2 u, const float2 s) {
  asm("v_pk_fma_f32 %0, %1, %2, %0 op_sel_hi:[0,1,1]\n\t"
      "v_pk_fma_f32 %0, %1, %2, %0 op_sel:[1,1,0] op_sel_hi:[1,0,1] neg_lo:[1,0,0]"
      : "+v"(o) : "v"(u), "v"(s));
}
// o = u * s (no accumulate); early-clobber since %0 is written before last read.
__device__ __forceinline__ float2 cmul(const float2 u, const float2 s) {
  float2 o;
  asm("v_pk_mul_f32 %0, %1, %2 op_sel_hi:[0,1]\n\t"
      "v_pk_fma_f32 %0, %1, %2, %0 op_sel:[1,1,0] op_sel_hi:[1,0,1] neg_lo:[1,0,0]"
      : "=&v"(o) : "v"(u), "v"(s));
  return o;
}

// ---------------------------------------------------------------------------
// Kernel A: U[k,b] = exp(-i * H_k * t_{k,b}),  H_k = 0.5*(A + A^H), A = Hr + i Hi
// 256 threads: 64 tasks (k,b) x 4 rows. Scaling (2^-4) + 8-term Taylor +
// 4 squarings (trunc error ~1e-10, invisible at fp32 / 2.1e-4 threshold).
// ---------------------------------------------------------------------------
__global__ __launch_bounds__(256) void compute_u_kernel(
    const float* __restrict__ Hre, const float* __restrict__ Him,
    const float* __restrict__ tevo, float* __restrict__ uout) {
  __shared__ float er_s[64][4][4];
  __shared__ float ei_s[64][4][4];

  const int tid  = threadIdx.x;   // 0..255
  const int task = tid >> 2;      // 0..63
  const int row  = tid & 3;       // 0..3
  const int k    = task >> 4;     // 0..3
  const int b    = task & 15;     // 0..15

  float Ar[4][4], Ai[4][4];
#pragma unroll
  for (int i = 0; i < 4; i++) {
#pragma unroll
    for (int j = 0; j < 4; j++) {
      Ar[i][j] = Hre[k * 16 + i * 4 + j];
      Ai[i][j] = Him[k * 16 + i * 4 + j];
    }
  }
  const float t = tevo[k * NB + b];
  const float ts = t * (1.0f / 16.0f);  // scale 2^-4 folded in

  // G = -i * H * ts ; H = 0.5*(A + A^H)
  float Gr[4][4], Gi[4][4];
#pragma unroll
  for (int i = 0; i < 4; i++) {
#pragma unroll
    for (int j = 0; j < 4; j++) {
      const float hr = 0.5f * (Ar[i][j] + Ar[j][i]);
      const float hi = 0.5f * (Ai[i][j] - Ai[j][i]);
      Gr[i][j] = ts * hi;
      Gi[i][j] = -ts * hr;
    }
  }

  // Taylor: E = I + sum_{m=1..8} G^m/m!   (row `row` only; full G in regs)
  float Er[4], Ei[4], Tr[4], Ti[4];
#pragma unroll
  for (int j = 0; j < 4; j++) {
    Er[j] = (j == row) ? 1.0f : 0.0f;
    Ei[j] = 0.0f;
    Tr[j] = Er[j];
    Ti[j] = 0.0f;
  }
#pragma unroll
  for (int m = 1; m <= 8; m++) {
    const float inv = 1.0f / (float)m;
    float nr[4], ni[4];
#pragma unroll
    for (int j = 0; j < 4; j++) {
      float ar = 0.0f, ai = 0.0f;
#pragma unroll
      for (int p = 0; p < 4; p++) {
        ar += Tr[p] * Gr[p][j] - Ti[p] * Gi[p][j];
        ai += Tr[p] * Gi[p][j] + Ti[p] * Gr[p][j];
      }
      nr[j] = ar * inv;
      ni[j] = ai * inv;
    }
#pragma unroll
    for (int j = 0; j < 4; j++) {
      Tr[j] = nr[j]; Ti[j] = ni[j];
      Er[j] += nr[j]; Ei[j] += ni[j];
    }
  }

  // 4 squarings via LDS (uniform trip count -> barriers are safe)
  for (int q = 0; q < 4; q++) {
    __syncthreads();
#pragma unroll
    for (int j = 0; j < 4; j++) {
      er_s[task][row][j] = Er[j];
      ei_s[task][row][j] = Ei[j];
    }
    __syncthreads();
    float nr[4], ni[4];
#pragma unroll
    for (int j = 0; j < 4; j++) {
      float ar = 0.0f, ai = 0.0f;
#pragma unroll
      for (int p = 0; p < 4; p++) {
        ar += Er[p] * er_s[task][p][j] - Ei[p] * ei_s[task][p][j];
        ai += Er[p] * ei_s[task][p][j] + Ei[p] * er_s[task][p][j];
      }
      nr[j] = ar; ni[j] = ai;
    }
#pragma unroll
    for (int j = 0; j < 4; j++) { Er[j] = nr[j]; Ei[j] = ni[j]; }
  }

  // Store U rows: layout [k][b][16 complex interleaved], row stride 36 floats
  const int ubase = (k * 16 + b) * USTRIDE;
#pragma unroll
  for (int j = 0; j < 4; j++) {
    uout[ubase + (row * 4 + j) * 2]     = Er[j];
    uout[ubase + (row * 4 + j) * 2 + 1] = Ei[j];
  }
}

// ---------------------------------------------------------------------------
// Kernel B (r14 compute core + 2-tile grid-stride, CORRECT reg clamp):
// two ADJACENT LANES per column (r,b); each owns one 16-g half.
// Block stages the 9 KiB U table ONCE (block-shared + one barrier), then
// loops over TILES=2 column-tiles of 128 cols. Grid = 2048 blocks.
// __launch_bounds__(256,4): 128-VGPR budget -- the only clamp that has
// never spilled here (r17's (256,8) forced 32 VGPR -> 5x regression).
// Gates k=1..3 half-local; k=0 cross term via DPP quad_perm; all complex
// MACs are 2x v_pk_fma_f32.
// ---------------------------------------------------------------------------
__global__ __launch_bounds__(256, 4) void apply_gates_kernel(
    const float* __restrict__ sre, const float* __restrict__ sim,
    const float* __restrict__ u, float* __restrict__ out) {
  __shared__ __align__(16) float ul[UTOT];          // 9216 B block-shared
  const int tid   = threadIdx.x;
  const int half  = tid & 1;                        // lanes alternate halves
  const int lcol  = tid >> 1;                       // 0..127 within tile
  const int b     = lcol & 15;
  const int gbase = half << 4;

  // stage U table once (9 KiB; UTOT = 9*256 exactly)
#pragma unroll
  for (int q = 0; q < 9; q++) ul[tid + q * 256] = u[tid + q * 256];
  __syncthreads();

  const float* ub0 = &ul[b * USTRIDE];   // k = 0 block
  const int h4 = half * 4;               // float offset of (j=2h) entry pair

  for (int t = 0; t < TILES; t++) {
    const int col = (blockIdx.x * TILES + t) * 128 + lcol;  // r*16 + b

    // own half: 16 complex -- one burst of 32 dword loads
    float2 s[16];
#pragma unroll
    for (int q = 0; q < 16; q++) {
      const int off = col + ((gbase + q) << 19);
      s[q].x = sre[off];
      s[q].y = sim[off];
    }

    float2 o[16];

    // ---- k = 0 (g bits [4:3]) : own term + DPP-exchanged cross term ----
    // own output g = half<<4 | b3<<3 | l : row i = 2*half + b3.
    // own sources s[l] (j=2*half), s[8+l] (j=2*half+1).
    // cross partial: my sources' contribution to partner output with row
    // i' = 2*(half^1) + b3; partner adds the DPP-swapped value.
#pragma unroll
    for (int b3 = 0; b3 < 2; b3++) {
      const float4 vo = *(const float4*)(ub0 + (half * 2 + b3) * 8 + h4);
      const float4 vc = *(const float4*)(ub0 + ((half ^ 1) * 2 + b3) * 8 + h4);
      const float2 vo0 = make_float2(vo.x, vo.y), vo1 = make_float2(vo.z, vo.w);
      const float2 vc0 = make_float2(vc.x, vc.y), vc1 = make_float2(vc.z, vc.w);
#pragma unroll
      for (int ll = 0; ll < 8; ll++) {
        const int gq = b3 * 8 + ll;
        o[gq] = cmul(vo0, s[ll]);
        cfma(o[gq], vo1, s[8 + ll]);
        float2 p = cmul(vc0, s[ll]);
        cfma(p, vc1, s[8 + ll]);
        o[gq].x += dpp_swap1(p.x);
        o[gq].y += dpp_swap1(p.y);
      }
    }

    // ---- k = 1..3: fully local to the half (bits [3:0] of g) ----
#pragma unroll
    for (int k = 1; k < 4; k++) {
      const int sh = 3 - k;  // 2, 1, 0
      const float* ub = &ul[(k * 16 + b) * USTRIDE];
#pragma unroll
      for (int i = 0; i < 4; i++) {
        const float4 v0 = *(const float4*)(ub + i * 8);      // j=0,1
        const float4 v1 = *(const float4*)(ub + i * 8 + 4);  // j=2,3
        const float2 u0 = make_float2(v0.x, v0.y), u1 = make_float2(v0.z, v0.w);
        const float2 u2 = make_float2(v1.x, v1.y), u3 = make_float2(v1.z, v1.w);
#pragma unroll
        for (int qq = 0; qq < 4; qq++) {
          const int low  = qq & ((1 << sh) - 1);
          const int high = (qq >> sh) << (sh + 2);
          const int gb   = high | low;           // gq with pair bits cleared
          const int gq   = gb | (i << sh);
          cfma(o[gq], u0, s[gb]);
          cfma(o[gq], u1, s[gb | (1 << sh)]);
          cfma(o[gq], u2, s[gb | (2 << sh)]);
          cfma(o[gq], u3, s[gb | (3 << sh)]);
        }
      }
    }

#pragma unroll
    for (int q = 0; q < 16; q++) {
      const int off = col + ((gbase + q) << 19);
      __builtin_nontemporal_store(o[q].x, out + off);               // real
      __builtin_nontemporal_store(o[q].y, out + off + (1 << 24));   // imag
    }
  }
}

extern "C" void kernel_launch(void* const* d_in, const int* in_sizes, int n_in,
                              void* d_out, int out_size, void* d_ws, size_t ws_size,
                              hipStream_t stream) {
  const float* Hre  = (const float*)d_in[0];
  const float* Him  = (const float*)d_in[1];
  const float* tevo = (const float*)d_in[2];
  const float* sre  = (const float*)d_in[3];
  const float* sim  = (const float*)d_in[4];
  float* out = (float*)d_out;
  float* uws = (float*)d_ws;  // UTOT floats = 9216 B

  compute_u_kernel<<<1, 256, 0, stream>>>(Hre, Him, tevo, uws);
  apply_gates_kernel<<<NBLK, 256, 0, stream>>>(sre, sim, uws, out);
}

// Round 19
// 53.827 us; speedup vs baseline: 4.9203x; 1.1239x over previous
//
#include <hip/hip_runtime.h>

// Problem constants
#define NQ 20
#define DIMQ (1 << NQ)          // 2^20
#define NB 16                   // BATCH
#define NT 4                    // N_TERMS
#define RBITS 15                // low bits untouched by gates
#define NCOL (1 << (RBITS + 4)) // 2^15 r-values * 16 batches = 524288 columns

// U table layout in ws/LDS: per (k,b): 36 floats (16 complex interleaved + 4 pad)
//   base = (k*16 + b) * 36 ; entry (i,j): re at base + (i*4+j)*2, im at +1
//   36 floats = 144 B = 9*16 B -> every (k,b) base is 16B-aligned; 2-way banks.
#define USTRIDE 36
#define UTOT (64 * USTRIDE)     // 2304 floats = 9216 B (= 576 float4 = 64 lanes x 9)

// lane <-> lane^1 exchange as DPP quad_perm [1,0,3,2] (0xB1): pure VALU.
__device__ __forceinline__ float dpp_swap1(float x) {
  int r = __builtin_amdgcn_mov_dpp(__builtin_bit_cast(int, x), 0xB1, 0xF, 0xF, true);
  return __builtin_bit_cast(float, r);
}

// Complex MAC via packed-FP32 VOP3P: o += u * s  (u=(ur,ui), s=(sr,si)).
__device__ __forceinline__ void cfma(float2& o, const float2 u, const float2 s) {
  asm("v_pk_fma_f32 %0, %1, %2, %0 op_sel_hi:[0,1,1]\n\t"
      "v_pk_fma_f32 %0, %1, %2, %0 op_sel:[1,1,0] op_sel_hi:[1,0,1] neg_lo:[1,0,0]"
      : "+v"(o) : "v"(u), "v"(s));
}
// o = u * s (no accumulate); early-clobber since %0 is written before last read.
__device__ __forceinline__ float2 cmul(const float2 u, const float2 s) {
  float2 o;
  asm("v_pk_mul_f32 %0, %1, %2 op_sel_hi:[0,1]\n\t"
      "v_pk_fma_f32 %0, %1, %2, %0 op_sel:[1,1,0] op_sel_hi:[1,0,1] neg_lo:[1,0,0]"
      : "=&v"(o) : "v"(u), "v"(s));
  return o;
}

// ---------------------------------------------------------------------------
// Kernel A: U[k,b] = exp(-i * H_k * t_{k,b}),  H_k = 0.5*(A + A^H), A = Hr + i Hi
// 256 threads: 64 tasks (k,b) x 4 rows. Scaling (2^-4) + 8-term Taylor +
// 4 squarings (trunc error ~1e-10, invisible at fp32 / 2.1e-4 threshold).
// ---------------------------------------------------------------------------
__global__ __launch_bounds__(256) void compute_u_kernel(
    const float* __restrict__ Hre, const float* __restrict__ Him,
    const float* __restrict__ tevo, float* __restrict__ uout) {
  __shared__ float er_s[64][4][4];
  __shared__ float ei_s[64][4][4];

  const int tid  = threadIdx.x;   // 0..255
  const int task = tid >> 2;      // 0..63
  const int row  = tid & 3;       // 0..3
  const int k    = task >> 4;     // 0..3
  const int b    = task & 15;     // 0..15

  float Ar[4][4], Ai[4][4];
#pragma unroll
  for (int i = 0; i < 4; i++) {
#pragma unroll
    for (int j = 0; j < 4; j++) {
      Ar[i][j] = Hre[k * 16 + i * 4 + j];
      Ai[i][j] = Him[k * 16 + i * 4 + j];
    }
  }
  const float t = tevo[k * NB + b];
  const float ts = t * (1.0f / 16.0f);  // scale 2^-4 folded in

  // G = -i * H * ts ; H = 0.5*(A + A^H)
  float Gr[4][4], Gi[4][4];
#pragma unroll
  for (int i = 0; i < 4; i++) {
#pragma unroll
    for (int j = 0; j < 4; j++) {
      const float hr = 0.5f * (Ar[i][j] + Ar[j][i]);
      const float hi = 0.5f * (Ai[i][j] - Ai[j][i]);
      Gr[i][j] = ts * hi;
      Gi[i][j] = -ts * hr;
    }
  }

  // Taylor: E = I + sum_{m=1..8} G^m/m!   (row `row` only; full G in regs)
  float Er[4], Ei[4], Tr[4], Ti[4];
#pragma unroll
  for (int j = 0; j < 4; j++) {
    Er[j] = (j == row) ? 1.0f : 0.0f;
    Ei[j] = 0.0f;
    Tr[j] = Er[j];
    Ti[j] = 0.0f;
  }
#pragma unroll
  for (int m = 1; m <= 8; m++) {
    const float inv = 1.0f / (float)m;
    float nr[4], ni[4];
#pragma unroll
    for (int j = 0; j < 4; j++) {
      float ar = 0.0f, ai = 0.0f;
#pragma unroll
      for (int p = 0; p < 4; p++) {
        ar += Tr[p] * Gr[p][j] - Ti[p] * Gi[p][j];
        ai += Tr[p] * Gi[p][j] + Ti[p] * Gr[p][j];
      }
      nr[j] = ar * inv;
      ni[j] = ai * inv;
    }
#pragma unroll
    for (int j = 0; j < 4; j++) {
      Tr[j] = nr[j]; Ti[j] = ni[j];
      Er[j] += nr[j]; Ei[j] += ni[j];
    }
  }

  // 4 squarings via LDS (uniform trip count -> barriers are safe)
  for (int q = 0; q < 4; q++) {
    __syncthreads();
#pragma unroll
    for (int j = 0; j < 4; j++) {
      er_s[task][row][j] = Er[j];
      ei_s[task][row][j] = Ei[j];
    }
    __syncthreads();
    float nr[4], ni[4];
#pragma unroll
    for (int j = 0; j < 4; j++) {
      float ar = 0.0f, ai = 0.0f;
#pragma unroll
      for (int p = 0; p < 4; p++) {
        ar += Er[p] * er_s[task][p][j] - Ei[p] * ei_s[task][p][j];
        ai += Er[p] * ei_s[task][p][j] + Ei[p] * er_s[task][p][j];
      }
      nr[j] = ar; ni[j] = ai;
    }
#pragma unroll
    for (int j = 0; j < 4; j++) { Er[j] = nr[j]; Ei[j] = ni[j]; }
  }

  // Store U rows: layout [k][b][16 complex interleaved], row stride 36 floats
  const int ubase = (k * 16 + b) * USTRIDE;
#pragma unroll
  for (int j = 0; j < 4; j++) {
    uout[ubase + (row * 4 + j) * 2]     = Er[j];
    uout[ubase + (row * 4 + j) * 2 + 1] = Ei[j];
  }
}

// ---------------------------------------------------------------------------
// Kernel B (r14 verbatim, single change: NT stores -> cached stores):
// two ADJACENT LANES per column (r,b); each owns one 16-g half.
// Per-wave U staging, no __syncthreads (waves drift freely). Gates k=1..3
// half-local; k=0 cross term via DPP quad_perm. All complex MACs are 2x
// v_pk_fma_f32. Stores are plain (L2 write-back): each store instr writes
// two FULL 128B lines, so no write-allocate penalty; waves retire at L2
// latency (~200cy) instead of HBM (~900cy) -> faster block turnaround.
// ---------------------------------------------------------------------------
__global__ __launch_bounds__(256, 4) void apply_gates_kernel(
    const float* __restrict__ sre, const float* __restrict__ sim,
    const float* __restrict__ u, float* __restrict__ out) {
  __shared__ __align__(16) float ul[4 * UTOT];      // 36864 B: one region/wave
  const int tid   = threadIdx.x;
  const int half  = tid & 1;                        // lanes alternate halves
  const int col   = blockIdx.x * 128 + (tid >> 1);  // r*16 + b
  const int b     = (tid >> 1) & 15;
  const int gbase = half << 4;

  // (1) own half: 16 complex -- one burst of 32 dword loads, issued FIRST
  float2 s[16];
#pragma unroll
  for (int q = 0; q < 16; q++) {
    const int off = col + ((gbase + q) << 19);
    s[q].x = sre[off];
    s[q].y = sim[off];
  }

  // (2) per-wave U staging: lane l copies float4s l, l+64, ..., l+512
  const int w = tid >> 6;
  const int l = tid & 63;
  float* uw = ul + w * UTOT;
  {
    const float4* u4 = (const float4*)u;
    float4* ul4 = (float4*)uw;
#pragma unroll
    for (int t = 0; t < 9; t++) ul4[l + 64 * t] = u4[l + 64 * t];
  }
  // no barrier: this wave only reads the region it just wrote (lgkmcnt).

  float2 o[16];

  // ---- k = 0 (g bits [4:3]) : own term + DPP-exchanged cross term ----
  // own output g = half<<4 | b3<<3 | l : row i = 2*half + b3.
  // own sources s[l] (j=2*half), s[8+l] (j=2*half+1).
  // cross partial: my sources' contribution to partner output with row
  // i' = 2*(half^1) + b3; partner adds the DPP-swapped value.
  {
    const float* ub0 = &uw[b * USTRIDE];  // k = 0 block
    const int h4 = half * 4;              // float offset of (j=2h) entry pair
#pragma unroll
    for (int b3 = 0; b3 < 2; b3++) {
      const float4 vo = *(const float4*)(ub0 + (half * 2 + b3) * 8 + h4);
      const float4 vc = *(const float4*)(ub0 + ((half ^ 1) * 2 + b3) * 8 + h4);
      const float2 vo0 = make_float2(vo.x, vo.y), vo1 = make_float2(vo.z, vo.w);
      const float2 vc0 = make_float2(vc.x, vc.y), vc1 = make_float2(vc.z, vc.w);
#pragma unroll
      for (int ll = 0; ll < 8; ll++) {
        const int gq = b3 * 8 + ll;
        o[gq] = cmul(vo0, s[ll]);
        cfma(o[gq], vo1, s[8 + ll]);
        float2 p = cmul(vc0, s[ll]);
        cfma(p, vc1, s[8 + ll]);
        o[gq].x += dpp_swap1(p.x);
        o[gq].y += dpp_swap1(p.y);
      }
    }
  }

  // ---- k = 1..3: fully local to the half (bits [3:0] of g) ----
#pragma unroll
  for (int k = 1; k < 4; k++) {
    const int sh = 3 - k;  // 2, 1, 0
    const float* ub = &uw[(k * 16 + b) * USTRIDE];
#pragma unroll
    for (int i = 0; i < 4; i++) {
      const float4 v0 = *(const float4*)(ub + i * 8);      // j=0,1
      const float4 v1 = *(const float4*)(ub + i * 8 + 4);  // j=2,3
      const float2 u0 = make_float2(v0.x, v0.y), u1 = make_float2(v0.z, v0.w);
      const float2 u2 = make_float2(v1.x, v1.y), u3 = make_float2(v1.z, v1.w);
#pragma unroll
      for (int qq = 0; qq < 4; qq++) {
        const int low  = qq & ((1 << sh) - 1);
        const int high = (qq >> sh) << (sh + 2);
        const int gb   = high | low;           // gq with pair bits cleared
        const int gq   = gb | (i << sh);
        cfma(o[gq], u0, s[gb]);
        cfma(o[gq], u1, s[gb | (1 << sh)]);
        cfma(o[gq], u2, s[gb | (2 << sh)]);
        cfma(o[gq], u3, s[gb | (3 << sh)]);
      }
    }
  }

  // cached stores: two full 128B lines per instruction, retire at L2
#pragma unroll
  for (int q = 0; q < 16; q++) {
    const int off = col + ((gbase + q) << 19);
    out[off] = o[q].x;                 // real
    out[off + (1 << 24)] = o[q].y;     // imag
  }
}

extern "C" void kernel_launch(void* const* d_in, const int* in_sizes, int n_in,
                              void* d_out, int out_size, void* d_ws, size_t ws_size,
                              hipStream_t stream) {
  const float* Hre  = (const float*)d_in[0];
  const float* Him  = (const float*)d_in[1];
  const float* tevo = (const float*)d_in[2];
  const float* sre  = (const float*)d_in[3];
  const float* sim  = (const float*)d_in[4];
  float* out = (float*)d_out;
  float* uws = (float*)d_ws;  // UTOT floats = 9216 B

  compute_u_kernel<<<1, 256, 0, stream>>>(Hre, Him, tevo, uws);
  apply_gates_kernel<<<NCOL / 128, 256, 0, stream>>>(sre, sim, uws, out);
}

// Round 20
// 53.208 us; speedup vs baseline: 4.9775x; 1.0116x over previous
//
#include <hip/hip_runtime.h>

// Problem constants
#define NQ 20
#define DIMQ (1 << NQ)          // 2^20
#define NB 16                   // BATCH
#define NT 4                    // N_TERMS
#define RBITS 15                // low bits untouched by gates
#define NCOL (1 << (RBITS + 4)) // 2^15 r-values * 16 batches = 524288 columns

// U table layout in ws/LDS: per (k,b): 36 floats (16 complex interleaved + 4 pad)
//   base = (k*16 + b) * 36 ; entry (i,j): re at base + (i*4+j)*2, im at +1
//   36 floats = 144 B = 9*16 B -> every (k,b) base is 16B-aligned; 2-way banks.
#define USTRIDE 36
#define UTOT (64 * USTRIDE)     // 2304 floats = 9216 B (= 576 float4 = 64 lanes x 9)

// lane <-> lane^1 exchange as DPP quad_perm [1,0,3,2] (0xB1): pure VALU.
__device__ __forceinline__ float dpp_swap1(float x) {
  int r = __builtin_amdgcn_mov_dpp(__builtin_bit_cast(int, x), 0xB1, 0xF, 0xF, true);
  return __builtin_bit_cast(float, r);
}

// Complex MAC via packed-FP32 VOP3P: o += u * s  (u=(ur,ui), s=(sr,si)).
__device__ __forceinline__ void cfma(float2& o, const float2 u, const float2 s) {
  asm("v_pk_fma_f32 %0, %1, %2, %0 op_sel_hi:[0,1,1]\n\t"
      "v_pk_fma_f32 %0, %1, %2, %0 op_sel:[1,1,0] op_sel_hi:[1,0,1] neg_lo:[1,0,0]"
      : "+v"(o) : "v"(u), "v"(s));
}
// o = u * s (no accumulate); early-clobber since %0 is written before last read.
__device__ __forceinline__ float2 cmul(const float2 u, const float2 s) {
  float2 o;
  asm("v_pk_mul_f32 %0, %1, %2 op_sel_hi:[0,1]\n\t"
      "v_pk_fma_f32 %0, %1, %2, %0 op_sel:[1,1,0] op_sel_hi:[1,0,1] neg_lo:[1,0,0]"
      : "=&v"(o) : "v"(u), "v"(s));
  return o;
}

// ---------------------------------------------------------------------------
// Kernel A: U[k,b] = exp(-i * H_k * t_{k,b}),  H_k = 0.5*(A + A^H), A = Hr + i Hi
// 256 threads: 64 tasks (k,b) x 4 rows. Scaling (2^-4) + 8-term Taylor +
// 4 squarings (trunc error ~1e-10, invisible at fp32 / 2.1e-4 threshold).
// ---------------------------------------------------------------------------
__global__ __launch_bounds__(256) void compute_u_kernel(
    const float* __restrict__ Hre, const float* __restrict__ Him,
    const float* __restrict__ tevo, float* __restrict__ uout) {
  __shared__ float er_s[64][4][4];
  __shared__ float ei_s[64][4][4];

  const int tid  = threadIdx.x;   // 0..255
  const int task = tid >> 2;      // 0..63
  const int row  = tid & 3;       // 0..3
  const int k    = task >> 4;     // 0..3
  const int b    = task & 15;     // 0..15

  float Ar[4][4], Ai[4][4];
#pragma unroll
  for (int i = 0; i < 4; i++) {
#pragma unroll
    for (int j = 0; j < 4; j++) {
      Ar[i][j] = Hre[k * 16 + i * 4 + j];
      Ai[i][j] = Him[k * 16 + i * 4 + j];
    }
  }
  const float t = tevo[k * NB + b];
  const float ts = t * (1.0f / 16.0f);  // scale 2^-4 folded in

  // G = -i * H * ts ; H = 0.5*(A + A^H)
  float Gr[4][4], Gi[4][4];
#pragma unroll
  for (int i = 0; i < 4; i++) {
#pragma unroll
    for (int j = 0; j < 4; j++) {
      const float hr = 0.5f * (Ar[i][j] + Ar[j][i]);
      const float hi = 0.5f * (Ai[i][j] - Ai[j][i]);
      Gr[i][j] = ts * hi;
      Gi[i][j] = -ts * hr;
    }
  }

  // Taylor: E = I + sum_{m=1..8} G^m/m!   (row `row` only; full G in regs)
  float Er[4], Ei[4], Tr[4], Ti[4];
#pragma unroll
  for (int j = 0; j < 4; j++) {
    Er[j] = (j == row) ? 1.0f : 0.0f;
    Ei[j] = 0.0f;
    Tr[j] = Er[j];
    Ti[j] = 0.0f;
  }
#pragma unroll
  for (int m = 1; m <= 8; m++) {
    const float inv = 1.0f / (float)m;
    float nr[4], ni[4];
#pragma unroll
    for (int j = 0; j < 4; j++) {
      float ar = 0.0f, ai = 0.0f;
#pragma unroll
      for (int p = 0; p < 4; p++) {
        ar += Tr[p] * Gr[p][j] - Ti[p] * Gi[p][j];
        ai += Tr[p] * Gi[p][j] + Ti[p] * Gr[p][j];
      }
      nr[j] = ar * inv;
      ni[j] = ai * inv;
    }
#pragma unroll
    for (int j = 0; j < 4; j++) {
      Tr[j] = nr[j]; Ti[j] = ni[j];
      Er[j] += nr[j]; Ei[j] += ni[j];
    }
  }

  // 4 squarings via LDS (uniform trip count -> barriers are safe)
  for (int q = 0; q < 4; q++) {
    __syncthreads();
#pragma unroll
    for (int j = 0; j < 4; j++) {
      er_s[task][row][j] = Er[j];
      ei_s[task][row][j] = Ei[j];
    }
    __syncthreads();
    float nr[4], ni[4];
#pragma unroll
    for (int j = 0; j < 4; j++) {
      float ar = 0.0f, ai = 0.0f;
#pragma unroll
      for (int p = 0; p < 4; p++) {
        ar += Er[p] * er_s[task][p][j] - Ei[p] * ei_s[task][p][j];
        ai += Er[p] * ei_s[task][p][j] + Ei[p] * er_s[task][p][j];
      }
      nr[j] = ar; ni[j] = ai;
    }
#pragma unroll
    for (int j = 0; j < 4; j++) { Er[j] = nr[j]; Ei[j] = ni[j]; }
  }

  // Store U rows: layout [k][b][16 complex interleaved], row stride 36 floats
  const int ubase = (k * 16 + b) * USTRIDE;
#pragma unroll
  for (int j = 0; j < 4; j++) {
    uout[ubase + (row * 4 + j) * 2]     = Er[j];
    uout[ubase + (row * 4 + j) * 2 + 1] = Ei[j];
  }
}

// ---------------------------------------------------------------------------
// Kernel B (r14 verbatim, single change: SHARED 9 KiB U region, still
// barrier-free): two ADJACENT LANES per column (r,b); each owns one 16-g
// half. EVERY wave performs the full 9-float4-per-lane U copy into the SAME
// 9 KiB region; a wave's reads are ordered after its OWN writes by the
// intra-wave lgkmcnt, and concurrent writes from other waves carry
// identical values, so any interleaving is correct -- no __syncthreads.
// LDS drops 36.9 -> 9.2 KiB, lifting the block cap 4 -> 8 blocks/CU
// (32 waves, thread-capped): double the latency-hiding pool for the
// ~600cy-per-load fold-into-use chain that dominates wave latency.
// Gates k=1..3 half-local; k=0 cross term via DPP quad_perm; all complex
// MACs are 2x v_pk_fma_f32; NT stores.
// ---------------------------------------------------------------------------
__global__ __launch_bounds__(256, 4) void apply_gates_kernel(
    const float* __restrict__ sre, const float* __restrict__ sim,
    const float* __restrict__ u, float* __restrict__ out) {
  __shared__ __align__(16) float ul[UTOT];          // 9216 B, shared by all waves
  const int tid   = threadIdx.x;
  const int half  = tid & 1;                        // lanes alternate halves
  const int col   = blockIdx.x * 128 + (tid >> 1);  // r*16 + b
  const int b     = (tid >> 1) & 15;
  const int gbase = half << 4;

  // (1) own half: 16 complex -- one burst of 32 dword loads, issued FIRST
  float2 s[16];
#pragma unroll
  for (int q = 0; q < 16; q++) {
    const int off = col + ((gbase + q) << 19);
    s[q].x = sre[off];
    s[q].y = sim[off];
  }

  // (2) U staging: every wave copies the full table into the SAME region
  //     (idempotent concurrent writes; reads ordered after own writes)
  const int l = tid & 63;
  {
    const float4* u4 = (const float4*)u;
    float4* ul4 = (float4*)ul;
#pragma unroll
    for (int t = 0; t < 9; t++) ul4[l + 64 * t] = u4[l + 64 * t];
  }
  // no barrier.

  float2 o[16];

  // ---- k = 0 (g bits [4:3]) : own term + DPP-exchanged cross term ----
  // own output g = half<<4 | b3<<3 | l : row i = 2*half + b3.
  // own sources s[l] (j=2*half), s[8+l] (j=2*half+1).
  // cross partial: my sources' contribution to partner output with row
  // i' = 2*(half^1) + b3; partner adds the DPP-swapped value.
  {
    const float* ub0 = &ul[b * USTRIDE];  // k = 0 block
    const int h4 = half * 4;              // float offset of (j=2h) entry pair
#pragma unroll
    for (int b3 = 0; b3 < 2; b3++) {
      const float4 vo = *(const float4*)(ub0 + (half * 2 + b3) * 8 + h4);
      const float4 vc = *(const float4*)(ub0 + ((half ^ 1) * 2 + b3) * 8 + h4);
      const float2 vo0 = make_float2(vo.x, vo.y), vo1 = make_float2(vo.z, vo.w);
      const float2 vc0 = make_float2(vc.x, vc.y), vc1 = make_float2(vc.z, vc.w);
#pragma unroll
      for (int ll = 0; ll < 8; ll++) {
        const int gq = b3 * 8 + ll;
        o[gq] = cmul(vo0, s[ll]);
        cfma(o[gq], vo1, s[8 + ll]);
        float2 p = cmul(vc0, s[ll]);
        cfma(p, vc1, s[8 + ll]);
        o[gq].x += dpp_swap1(p.x);
        o[gq].y += dpp_swap1(p.y);
      }
    }
  }

  // ---- k = 1..3: fully local to the half (bits [3:0] of g) ----
#pragma unroll
  for (int k = 1; k < 4; k++) {
    const int sh = 3 - k;  // 2, 1, 0
    const float* ub = &ul[(k * 16 + b) * USTRIDE];
#pragma unroll
    for (int i = 0; i < 4; i++) {
      const float4 v0 = *(const float4*)(ub + i * 8);      // j=0,1
      const float4 v1 = *(const float4*)(ub + i * 8 + 4);  // j=2,3
      const float2 u0 = make_float2(v0.x, v0.y), u1 = make_float2(v0.z, v0.w);
      const float2 u2 = make_float2(v1.x, v1.y), u3 = make_float2(v1.z, v1.w);
#pragma unroll
      for (int qq = 0; qq < 4; qq++) {
        const int low  = qq & ((1 << sh) - 1);
        const int high = (qq >> sh) << (sh + 2);
        const int gb   = high | low;           // gq with pair bits cleared
        const int gq   = gb | (i << sh);
        cfma(o[gq], u0, s[gb]);
        cfma(o[gq], u1, s[gb | (1 << sh)]);
        cfma(o[gq], u2, s[gb | (2 << sh)]);
        cfma(o[gq], u3, s[gb | (3 << sh)]);
      }
    }
  }

#pragma unroll
  for (int q = 0; q < 16; q++) {
    const int off = col + ((gbase + q) << 19);
    __builtin_nontemporal_store(o[q].x, out + off);               // real
    __builtin_nontemporal_store(o[q].y, out + off + (1 << 24));   // imag
  }
}

extern "C" void kernel_launch(void* const* d_in, const int* in_sizes, int n_in,
                              void* d_out, int out_size, void* d_ws, size_t ws_size,
                              hipStream_t stream) {
  const float* Hre  = (const float*)d_in[0];
  const float* Him  = (const float*)d_in[1];
  const float* tevo = (const float*)d_in[2];
  const float* sre  = (const float*)d_in[3];
  const float* sim  = (const float*)d_in[4];
  float* out = (float*)d_out;
  float* uws = (float*)d_ws;  // UTOT floats = 9216 B

  compute_u_kernel<<<1, 256, 0, stream>>>(Hre, Him, tevo, uws);
  apply_gates_kernel<<<NCOL / 128, 256, 0, stream>>>(sre, sim, uws, out);
}

// Round 21
// 51.142 us; speedup vs baseline: 5.1786x; 1.0404x over previous
//
#include <hip/hip_runtime.h>

// Problem constants
#define NQ 20
#define DIMQ (1 << NQ)          // 2^20
#define NB 16                   // BATCH
#define NT 4                    // N_TERMS
#define RBITS 15                // low bits untouched by gates
#define NCOL (1 << (RBITS + 4)) // 2^15 r-values * 16 batches = 524288 columns

// U table layout in ws/LDS: per (k,b): 36 floats (16 complex interleaved + 4 pad)
//   base = (k*16 + b) * 36 ; entry (i,j): re at base + (i*4+j)*2, im at +1
#define USTRIDE 36
#define UTOT (64 * USTRIDE)     // 2304 floats = 9216 B

// Complex MAC via packed-FP32 VOP3P: o += u * s  (u=(ur,ui), s=(sr,si)).
__device__ __forceinline__ void cfma(float2& o, const float2 u, const float2 s) {
  asm("v_pk_fma_f32 %0, %1, %2, %0 op_sel_hi:[0,1,1]\n\t"
      "v_pk_fma_f32 %0, %1, %2, %0 op_sel:[1,1,0] op_sel_hi:[1,0,1] neg_lo:[1,0,0]"
      : "+v"(o) : "v"(u), "v"(s));
}
// o = u * s (no accumulate); early-clobber since %0 is written before last read.
__device__ __forceinline__ float2 cmul(const float2 u, const float2 s) {
  float2 o;
  asm("v_pk_mul_f32 %0, %1, %2 op_sel_hi:[0,1]\n\t"
      "v_pk_fma_f32 %0, %1, %2, %0 op_sel:[1,1,0] op_sel_hi:[1,0,1] neg_lo:[1,0,0]"
      : "=&v"(o) : "v"(u), "v"(s));
  return o;
}

// ---------------------------------------------------------------------------
// Kernel A: U[k,b] = exp(-i * H_k * t_{k,b}),  H_k = 0.5*(A + A^H), A = Hr + i Hi
// 256 threads: 64 tasks (k,b) x 4 rows. Scaling (2^-4) + 8-term Taylor +
// 4 squarings (trunc error ~1e-10, invisible at fp32 / 2.1e-4 threshold).
// ---------------------------------------------------------------------------
__global__ __launch_bounds__(256) void compute_u_kernel(
    const float* __restrict__ Hre, const float* __restrict__ Him,
    const float* __restrict__ tevo, float* __restrict__ uout) {
  __shared__ float er_s[64][4][4];
  __shared__ float ei_s[64][4][4];

  const int tid  = threadIdx.x;   // 0..255
  const int task = tid >> 2;      // 0..63
  const int row  = tid & 3;       // 0..3
  const int k    = task >> 4;     // 0..3
  const int b    = task & 15;     // 0..15

  float Ar[4][4], Ai[4][4];
#pragma unroll
  for (int i = 0; i < 4; i++) {
#pragma unroll
    for (int j = 0; j < 4; j++) {
      Ar[i][j] = Hre[k * 16 + i * 4 + j];
      Ai[i][j] = Him[k * 16 + i * 4 + j];
    }
  }
  const float t = tevo[k * NB + b];
  const float ts = t * (1.0f / 16.0f);  // scale 2^-4 folded in

  // G = -i * H * ts ; H = 0.5*(A + A^H)
  float Gr[4][4], Gi[4][4];
#pragma unroll
  for (int i = 0; i < 4; i++) {
#pragma unroll
    for (int j = 0; j < 4; j++) {
      const float hr = 0.5f * (Ar[i][j] + Ar[j][i]);
      const float hi = 0.5f * (Ai[i][j] - Ai[j][i]);
      Gr[i][j] = ts * hi;
      Gi[i][j] = -ts * hr;
    }
  }

  // Taylor: E = I + sum_{m=1..8} G^m/m!   (row `row` only; full G in regs)
  float Er[4], Ei[4], Tr[4], Ti[4];
#pragma unroll
  for (int j = 0; j < 4; j++) {
    Er[j] = (j == row) ? 1.0f : 0.0f;
    Ei[j] = 0.0f;
    Tr[j] = Er[j];
    Ti[j] = 0.0f;
  }
#pragma unroll
  for (int m = 1; m <= 8; m++) {
    const float inv = 1.0f / (float)m;
    float nr[4], ni[4];
#pragma unroll
    for (int j = 0; j < 4; j++) {
      float ar = 0.0f, ai = 0.0f;
#pragma unroll
      for (int p = 0; p < 4; p++) {
        ar += Tr[p] * Gr[p][j] - Ti[p] * Gi[p][j];
        ai += Tr[p] * Gi[p][j] + Ti[p] * Gr[p][j];
      }
      nr[j] = ar * inv;
      ni[j] = ai * inv;
    }
#pragma unroll
    for (int j = 0; j < 4; j++) {
      Tr[j] = nr[j]; Ti[j] = ni[j];
      Er[j] += nr[j]; Ei[j] += ni[j];
    }
  }

  // 4 squarings via LDS (uniform trip count -> barriers are safe)
  for (int q = 0; q < 4; q++) {
    __syncthreads();
#pragma unroll
    for (int j = 0; j < 4; j++) {
      er_s[task][row][j] = Er[j];
      ei_s[task][row][j] = Ei[j];
    }
    __syncthreads();
    float nr[4], ni[4];
#pragma unroll
    for (int j = 0; j < 4; j++) {
      float ar = 0.0f, ai = 0.0f;
#pragma unroll
      for (int p = 0; p < 4; p++) {
        ar += Er[p] * er_s[task][p][j] - Ei[p] * ei_s[task][p][j];
        ai += Er[p] * ei_s[task][p][j] + Ei[p] * er_s[task][p][j];
      }
      nr[j] = ar; ni[j] = ai;
    }
#pragma unroll
    for (int j = 0; j < 4; j++) { Er[j] = nr[j]; Ei[j] = ni[j]; }
  }

  // Store U rows: layout [k][b][16 complex interleaved], row stride 36 floats
  const int ubase = (k * 16 + b) * USTRIDE;
#pragma unroll
  for (int j = 0; j < 4; j++) {
    uout[ubase + (row * 4 + j) * 2]     = Er[j];
    uout[ubase + (row * 4 + j) * 2 + 1] = Ei[j];
  }
}

// ---------------------------------------------------------------------------
// Kernel B (quarter-column threads + DMA-staged state + wave-aligned planes):
// Block = 64 columns; wave w owns g-quadrant w (planes g = w*8..w*8+7), lane
// l owns column c0+l. State tile [plane][64 cols] (planes 0..31 re, 32..63
// im; 16 KiB) staged by 16 global_load_lds width-16 instrs (zero VGPR cost,
// linear lane*16B dest). One barrier. All operand reads afterwards are LDS
// (~120cy folds, stride-1 conflict-free); per-thread live set = own 8
// complex + 8-complex acc + phase temps (~48 floats) -> no fold-churn.
//   k=3 (g[1:0]), k=2 (g[2:1]): in-thread on own quadrant.
//   k=1 (g[3:2]): bit3 -> partner quadrant w^1 read from LDS (reused for
//                 k=0's j=w^1 term while live).
//   k=0 (g[4:3]): o[m] += U0[w][j]*quad_j[m]; j=w from regs, j=w^2,w^3 LDS.
// Loads AND stores are 64-lane x 4B contiguous (256B/instr, full lines).
// LDS 25.6 KB -> 6 blocks/CU (24 waves, 75% occ). pk-FMA math; NT stores.
// ---------------------------------------------------------------------------
__global__ __launch_bounds__(256, 4) void apply_gates_kernel(
    const float* __restrict__ sre, const float* __restrict__ sim,
    const float* __restrict__ u, float* __restrict__ out) {
  __shared__ __align__(16) float ul[UTOT];      // 9216 B U table
  __shared__ __align__(16) float st[64 * 64];   // 16 KiB state tile [pl][col]
  const int tid = threadIdx.x;
  const int w   = tid >> 6;     // wave = owned quadrant (g bits [4:3])
  const int l   = tid & 63;     // lane = column within block
  const int c0  = blockIdx.x * 64;
  const int b   = l & 15;
  const int q0  = w & 1;        // g bit 3

  // (1) DMA the state tile: 4 instrs/wave, 1 KiB each (4 planes/instr).
  //     instr p: planes 4p..4p+3; lane l -> plane 4p+(l>>4), cols (l&15)*4..+3.
#pragma unroll
  for (int t = 0; t < 4; t++) {
    const int p  = w * 4 + t;            // 0..15, wave-uniform
    const int pl = p * 4 + (l >> 4);     // 0..63 (4-aligned group never crosses 32)
    const int g  = pl & 31;
    const float* src = (pl < 32 ? sre : sim) + (g << 19) + c0 + (l & 15) * 4;
    float* dst = st + p * 256;           // wave-uniform base, lane*16B implicit
    __builtin_amdgcn_global_load_lds(
        (const __attribute__((address_space(1))) float*)(const void*)src,
        (__attribute__((address_space(3))) float*)(void*)dst, 16, 0, 0);
  }

  // (2) stage U table cooperatively (barrier below orders it)
#pragma unroll
  for (int q = 0; q < 9; q++) ul[tid + q * 256] = u[tid + q * 256];

  __syncthreads();   // drains DMA (vmcnt) + U writes (lgkmcnt)

  // (3) own quadrant into registers: 16 conflict-free scalar LDS reads
  float2 s[8];
#pragma unroll
  for (int m = 0; m < 8; m++) {
    s[m].x = st[(w * 8 + m) * 64 + l];
    s[m].y = st[(32 + w * 8 + m) * 64 + l];
  }

  float2 o[8];

  // ---- k = 3 (g bits [1:0]) : in-thread; initializes acc ----
  // o[h*4+i] = sum_j U3[i][j] * s[h*4+j]
  {
    const float* ub = &ul[(3 * 16 + b) * USTRIDE];
#pragma unroll
    for (int i = 0; i < 4; i++) {
      const float4 v0 = *(const float4*)(ub + i * 8);
      const float4 v1 = *(const float4*)(ub + i * 8 + 4);
      const float2 u0 = make_float2(v0.x, v0.y), u1 = make_float2(v0.z, v0.w);
      const float2 u2 = make_float2(v1.x, v1.y), u3 = make_float2(v1.z, v1.w);
#pragma unroll
      for (int h = 0; h < 2; h++) {
        const int om = h * 4 + i;
        o[om] = cmul(u0, s[h * 4 + 0]);
        cfma(o[om], u1, s[h * 4 + 1]);
        cfma(o[om], u2, s[h * 4 + 2]);
        cfma(o[om], u3, s[h * 4 + 3]);
      }
    }
  }

  // ---- k = 2 (g bits [2:1]) : in-thread ----
  // o[i*2+l0] += sum_j U2[i][j] * s[j*2+l0]
  {
    const float* ub = &ul[(2 * 16 + b) * USTRIDE];
#pragma unroll
    for (int i = 0; i < 4; i++) {
      const float4 v0 = *(const float4*)(ub + i * 8);
      const float4 v1 = *(const float4*)(ub + i * 8 + 4);
      const float2 u0 = make_float2(v0.x, v0.y), u1 = make_float2(v0.z, v0.w);
      const float2 u2 = make_float2(v1.x, v1.y), u3 = make_float2(v1.z, v1.w);
#pragma unroll
      for (int l0 = 0; l0 < 2; l0++) {
        const int om = i * 2 + l0;
        cfma(o[om], u0, s[l0]);
        cfma(o[om], u1, s[2 + l0]);
        cfma(o[om], u2, s[4 + l0]);
        cfma(o[om], u3, s[6 + l0]);
      }
    }
  }

  // ---- k = 1 (g bits [3:2]) + k = 0's j=w^1 term (reuses p[]) ----
  // out i = q0*2 + (m>>2); src bits[3:2]=(j3,j2): j3=q0 -> own s, j3=q0^1 ->
  // partner quadrant w^1 (p[], read from LDS).
  {
    float2 p[8];
    const int pq = w ^ 1;
#pragma unroll
    for (int m = 0; m < 8; m++) {
      p[m].x = st[(pq * 8 + m) * 64 + l];
      p[m].y = st[(32 + pq * 8 + m) * 64 + l];
    }
    const float* ub1 = &ul[(1 * 16 + b) * USTRIDE];
#pragma unroll
    for (int mh = 0; mh < 2; mh++) {
      const int i = q0 * 2 + mh;
      const float* row = ub1 + i * 8;
#pragma unroll
      for (int j2 = 0; j2 < 2; j2++) {
        const float2 uo = *(const float2*)(row + (q0 * 2 + j2) * 2);
        const float2 up = *(const float2*)(row + ((q0 ^ 1) * 2 + j2) * 2);
#pragma unroll
        for (int ml = 0; ml < 4; ml++) {
          const int om = mh * 4 + ml;
          cfma(o[om], uo, s[j2 * 4 + ml]);
          cfma(o[om], up, p[j2 * 4 + ml]);
        }
      }
    }
    // k=0 term j = w^1 while p[] is live: o[m] += U0[w][w^1] * p[m]
    const float* ub0 = &ul[b * USTRIDE];
    const float2 u01 = *(const float2*)(ub0 + (w * 4 + (w ^ 1)) * 2);
#pragma unroll
    for (int m = 0; m < 8; m++) cfma(o[m], u01, p[m]);
  }

  // ---- k = 0 remaining: j = w (own regs), j = w^2, w^3 (LDS) ----
  {
    const float* ub0 = &ul[b * USTRIDE];
    const float2 u00 = *(const float2*)(ub0 + (w * 4 + w) * 2);
#pragma unroll
    for (int m = 0; m < 8; m++) cfma(o[m], u00, s[m]);
#pragma unroll
    for (int d = 2; d < 4; d++) {
      const int jq = w ^ d;
      const float2 uj = *(const float2*)(ub0 + (w * 4 + jq) * 2);
#pragma unroll
      for (int m = 0; m < 8; m++) {
        float2 t;
        t.x = st[(jq * 8 + m) * 64 + l];
        t.y = st[(32 + jq * 8 + m) * 64 + l];
        cfma(o[m], uj, t);
      }
    }
  }

  // stores: 64 lanes x 4B contiguous = 256B (full lines) per instruction
#pragma unroll
  for (int m = 0; m < 8; m++) {
    const int off = c0 + l + ((w * 8 + m) << 19);
    __builtin_nontemporal_store(o[m].x, out + off);               // real
    __builtin_nontemporal_store(o[m].y, out + off + (1 << 24));   // imag
  }
}

extern "C" void kernel_launch(void* const* d_in, const int* in_sizes, int n_in,
                              void* d_out, int out_size, void* d_ws, size_t ws_size,
                              hipStream_t stream) {
  const float* Hre  = (const float*)d_in[0];
  const float* Him  = (const float*)d_in[1];
  const float* tevo = (const float*)d_in[2];
  const float* sre  = (const float*)d_in[3];
  const float* sim  = (const float*)d_in[4];
  float* out = (float*)d_out;
  float* uws = (float*)d_ws;  // UTOT floats = 9216 B

  compute_u_kernel<<<1, 256, 0, stream>>>(Hre, Him, tevo, uws);
  apply_gates_kernel<<<NCOL / 64, 256, 0, stream>>>(sre, sim, uws, out);
}

// Round 22
// 50.202 us; speedup vs baseline: 5.2756x; 1.0187x over previous
//
#include <hip/hip_runtime.h>

// Problem constants
#define NQ 20
#define DIMQ (1 << NQ)          // 2^20
#define NB 16                   // BATCH
#define NT 4                    // N_TERMS
#define RBITS 15                // low bits untouched by gates
#define NCOL (1 << (RBITS + 4)) // 2^15 r-values * 16 batches = 524288 columns

// U table layout in ws/LDS: per (k,b): 36 floats (16 complex interleaved + 4 pad)
//   base = (k*16 + b) * 36 ; entry (i,j): re at base + (i*4+j)*2, im at +1
#define USTRIDE 36
#define UTOT (64 * USTRIDE)     // 2304 floats = 9216 B

// Complex MAC via packed-FP32 VOP3P: o += u * s  (u=(ur,ui), s=(sr,si)).
__device__ __forceinline__ void cfma(float2& o, const float2 u, const float2 s) {
  asm("v_pk_fma_f32 %0, %1, %2, %0 op_sel_hi:[0,1,1]\n\t"
      "v_pk_fma_f32 %0, %1, %2, %0 op_sel:[1,1,0] op_sel_hi:[1,0,1] neg_lo:[1,0,0]"
      : "+v"(o) : "v"(u), "v"(s));
}
// o = u * s (no accumulate); early-clobber since %0 is written before last read.
__device__ __forceinline__ float2 cmul(const float2 u, const float2 s) {
  float2 o;
  asm("v_pk_mul_f32 %0, %1, %2 op_sel_hi:[0,1]\n\t"
      "v_pk_fma_f32 %0, %1, %2, %0 op_sel:[1,1,0] op_sel_hi:[1,0,1] neg_lo:[1,0,0]"
      : "=&v"(o) : "v"(u), "v"(s));
  return o;
}

// ---------------------------------------------------------------------------
// Kernel A: U[k,b] = exp(-i * H_k * t_{k,b}),  H_k = 0.5*(A + A^H), A = Hr + i Hi
// 256 threads: 64 tasks (k,b) x 4 rows. Scaling (2^-4) + 8-term Taylor +
// 4 squarings (trunc error ~1e-10, invisible at fp32 / 2.1e-4 threshold).
// ---------------------------------------------------------------------------
__global__ __launch_bounds__(256) void compute_u_kernel(
    const float* __restrict__ Hre, const float* __restrict__ Him,
    const float* __restrict__ tevo, float* __restrict__ uout) {
  __shared__ float er_s[64][4][4];
  __shared__ float ei_s[64][4][4];

  const int tid  = threadIdx.x;   // 0..255
  const int task = tid >> 2;      // 0..63
  const int row  = tid & 3;       // 0..3
  const int k    = task >> 4;     // 0..3
  const int b    = task & 15;     // 0..15

  float Ar[4][4], Ai[4][4];
#pragma unroll
  for (int i = 0; i < 4; i++) {
#pragma unroll
    for (int j = 0; j < 4; j++) {
      Ar[i][j] = Hre[k * 16 + i * 4 + j];
      Ai[i][j] = Him[k * 16 + i * 4 + j];
    }
  }
  const float t = tevo[k * NB + b];
  const float ts = t * (1.0f / 16.0f);  // scale 2^-4 folded in

  // G = -i * H * ts ; H = 0.5*(A + A^H)
  float Gr[4][4], Gi[4][4];
#pragma unroll
  for (int i = 0; i < 4; i++) {
#pragma unroll
    for (int j = 0; j < 4; j++) {
      const float hr = 0.5f * (Ar[i][j] + Ar[j][i]);
      const float hi = 0.5f * (Ai[i][j] - Ai[j][i]);
      Gr[i][j] = ts * hi;
      Gi[i][j] = -ts * hr;
    }
  }

  // Taylor: E = I + sum_{m=1..8} G^m/m!   (row `row` only; full G in regs)
  float Er[4], Ei[4], Tr[4], Ti[4];
#pragma unroll
  for (int j = 0; j < 4; j++) {
    Er[j] = (j == row) ? 1.0f : 0.0f;
    Ei[j] = 0.0f;
    Tr[j] = Er[j];
    Ti[j] = 0.0f;
  }
#pragma unroll
  for (int m = 1; m <= 8; m++) {
    const float inv = 1.0f / (float)m;
    float nr[4], ni[4];
#pragma unroll
    for (int j = 0; j < 4; j++) {
      float ar = 0.0f, ai = 0.0f;
#pragma unroll
      for (int p = 0; p < 4; p++) {
        ar += Tr[p] * Gr[p][j] - Ti[p] * Gi[p][j];
        ai += Tr[p] * Gi[p][j] + Ti[p] * Gr[p][j];
      }
      nr[j] = ar * inv;
      ni[j] = ai * inv;
    }
#pragma unroll
    for (int j = 0; j < 4; j++) {
      Tr[j] = nr[j]; Ti[j] = ni[j];
      Er[j] += nr[j]; Ei[j] += ni[j];
    }
  }

  // 4 squarings via LDS (uniform trip count -> barriers are safe)
  for (int q = 0; q < 4; q++) {
    __syncthreads();
#pragma unroll
    for (int j = 0; j < 4; j++) {
      er_s[task][row][j] = Er[j];
      ei_s[task][row][j] = Ei[j];
    }
    __syncthreads();
    float nr[4], ni[4];
#pragma unroll
    for (int j = 0; j < 4; j++) {
      float ar = 0.0f, ai = 0.0f;
#pragma unroll
      for (int p = 0; p < 4; p++) {
        ar += Er[p] * er_s[task][p][j] - Ei[p] * ei_s[task][p][j];
        ai += Er[p] * ei_s[task][p][j] + Ei[p] * er_s[task][p][j];
      }
      nr[j] = ar; ni[j] = ai;
    }
#pragma unroll
    for (int j = 0; j < 4; j++) { Er[j] = nr[j]; Ei[j] = ni[j]; }
  }

  // Store U rows: layout [k][b][16 complex interleaved], row stride 36 floats
  const int ubase = (k * 16 + b) * USTRIDE;
#pragma unroll
  for (int j = 0; j < 4; j++) {
    uout[ubase + (row * 4 + j) * 2]     = Er[j];
    uout[ubase + (row * 4 + j) * 2 + 1] = Ei[j];
  }
}

// ---------------------------------------------------------------------------
// Kernel B (r21 + interleaved re/im tile -> paired LDS reads):
// Block = 64 columns; wave w owns g-quadrant w (g = w*8..w*8+7), lane l owns
// column c0+l. State tile layout: [g][re x64 | im x64] (128 floats/plane,
// 16 KiB total). DMA: 16 global_load_lds width-16 instrs; instr p covers
// planes 2p,2p+1 with PER-LANE source selection (lanes 0-15 re(2p),
// 16-31 im(2p), 32-47 re(2p+1), 48-63 im(2p+1)) -- the LDS dest is the
// required linear lane*16B, the global src is free per-lane (m104).
// Each (re,im) state read is then a fused ds_read2_b32 (offset delta 64
// dwords): state LDS reads drop 64 -> 32 instrs/thread, halving the
// LDS-pipe time (~720 -> ~530 cy/wave) that r21's arithmetic says binds.
// Gate math, U staging, NT stores: r21-verbatim.
// ---------------------------------------------------------------------------
__global__ __launch_bounds__(256, 4) void apply_gates_kernel(
    const float* __restrict__ sre, const float* __restrict__ sim,
    const float* __restrict__ u, float* __restrict__ out) {
  __shared__ __align__(16) float ul[UTOT];      // 9216 B U table
  __shared__ __align__(16) float st[32 * 128];  // 16 KiB tile [g][re64|im64]
  const int tid = threadIdx.x;
  const int w   = tid >> 6;     // wave = owned quadrant (g bits [4:3])
  const int l   = tid & 63;     // lane = column within block
  const int c0  = blockIdx.x * 64;
  const int b   = l & 15;
  const int q0  = w & 1;        // g bit 3

  // (1) DMA the state tile: 4 instrs/wave, 1 KiB each (2 planes/instr).
  //     instr p: sub = l>>4; g = 2p + (sub>>1); sub&1 ? im : re;
  //     cols (l&15)*4 .. +3 ; dest = st + p*256 floats (linear lane*16B).
#pragma unroll
  for (int t = 0; t < 4; t++) {
    const int p   = w * 4 + t;            // 0..15, wave-uniform
    const int sub = l >> 4;               // 0..3
    const int g   = 2 * p + (sub >> 1);   // 0..31
    const float* base = (sub & 1) ? sim : sre;
    const float* src  = base + (g << 19) + c0 + (l & 15) * 4;
    float* dst = st + p * 256;            // wave-uniform base, lane*16B implicit
    __builtin_amdgcn_global_load_lds(
        (const __attribute__((address_space(1))) float*)(const void*)src,
        (__attribute__((address_space(3))) float*)(void*)dst, 16, 0, 0);
  }

  // (2) stage U table cooperatively (barrier below orders it)
#pragma unroll
  for (int q = 0; q < 9; q++) ul[tid + q * 256] = u[tid + q * 256];

  __syncthreads();   // drains DMA (vmcnt) + U writes (lgkmcnt)

  // (3) own quadrant into registers: 8 paired reads (ds_read2_b32)
  float2 s[8];
#pragma unroll
  for (int m = 0; m < 8; m++) {
    const int a = (w * 8 + m) * 128 + l;
    s[m].x = st[a];
    s[m].y = st[a + 64];
  }

  float2 o[8];

  // ---- k = 3 (g bits [1:0]) : in-thread; initializes acc ----
  // o[h*4+i] = sum_j U3[i][j] * s[h*4+j]
  {
    const float* ub = &ul[(3 * 16 + b) * USTRIDE];
#pragma unroll
    for (int i = 0; i < 4; i++) {
      const float4 v0 = *(const float4*)(ub + i * 8);
      const float4 v1 = *(const float4*)(ub + i * 8 + 4);
      const float2 u0 = make_float2(v0.x, v0.y), u1 = make_float2(v0.z, v0.w);
      const float2 u2 = make_float2(v1.x, v1.y), u3 = make_float2(v1.z, v1.w);
#pragma unroll
      for (int h = 0; h < 2; h++) {
        const int om = h * 4 + i;
        o[om] = cmul(u0, s[h * 4 + 0]);
        cfma(o[om], u1, s[h * 4 + 1]);
        cfma(o[om], u2, s[h * 4 + 2]);
        cfma(o[om], u3, s[h * 4 + 3]);
      }
    }
  }

  // ---- k = 2 (g bits [2:1]) : in-thread ----
  // o[i*2+l0] += sum_j U2[i][j] * s[j*2+l0]
  {
    const float* ub = &ul[(2 * 16 + b) * USTRIDE];
#pragma unroll
    for (int i = 0; i < 4; i++) {
      const float4 v0 = *(const float4*)(ub + i * 8);
      const float4 v1 = *(const float4*)(ub + i * 8 + 4);
      const float2 u0 = make_float2(v0.x, v0.y), u1 = make_float2(v0.z, v0.w);
      const float2 u2 = make_float2(v1.x, v1.y), u3 = make_float2(v1.z, v1.w);
#pragma unroll
      for (int l0 = 0; l0 < 2; l0++) {
        const int om = i * 2 + l0;
        cfma(o[om], u0, s[l0]);
        cfma(o[om], u1, s[2 + l0]);
        cfma(o[om], u2, s[4 + l0]);
        cfma(o[om], u3, s[6 + l0]);
      }
    }
  }

  // ---- k = 1 (g bits [3:2]) + k = 0's j=w^1 term (reuses p[]) ----
  // out i = q0*2 + (m>>2); src bits[3:2]=(j3,j2): j3=q0 -> own s, j3=q0^1 ->
  // partner quadrant w^1 (p[], paired LDS reads).
  {
    float2 p[8];
    const int pq = w ^ 1;
#pragma unroll
    for (int m = 0; m < 8; m++) {
      const int a = (pq * 8 + m) * 128 + l;
      p[m].x = st[a];
      p[m].y = st[a + 64];
    }
    const float* ub1 = &ul[(1 * 16 + b) * USTRIDE];
#pragma unroll
    for (int mh = 0; mh < 2; mh++) {
      const int i = q0 * 2 + mh;
      const float* row = ub1 + i * 8;
#pragma unroll
      for (int j2 = 0; j2 < 2; j2++) {
        const float2 uo = *(const float2*)(row + (q0 * 2 + j2) * 2);
        const float2 up = *(const float2*)(row + ((q0 ^ 1) * 2 + j2) * 2);
#pragma unroll
        for (int ml = 0; ml < 4; ml++) {
          const int om = mh * 4 + ml;
          cfma(o[om], uo, s[j2 * 4 + ml]);
          cfma(o[om], up, p[j2 * 4 + ml]);
        }
      }
    }
    // k=0 term j = w^1 while p[] is live: o[m] += U0[w][w^1] * p[m]
    const float* ub0 = &ul[b * USTRIDE];
    const float2 u01 = *(const float2*)(ub0 + (w * 4 + (w ^ 1)) * 2);
#pragma unroll
    for (int m = 0; m < 8; m++) cfma(o[m], u01, p[m]);
  }

  // ---- k = 0 remaining: j = w (own regs), j = w^2, w^3 (paired LDS) ----
  {
    const float* ub0 = &ul[b * USTRIDE];
    const float2 u00 = *(const float2*)(ub0 + (w * 4 + w) * 2);
#pragma unroll
    for (int m = 0; m < 8; m++) cfma(o[m], u00, s[m]);
#pragma unroll
    for (int d = 2; d < 4; d++) {
      const int jq = w ^ d;
      const float2 uj = *(const float2*)(ub0 + (w * 4 + jq) * 2);
#pragma unroll
      for (int m = 0; m < 8; m++) {
        const int a = (jq * 8 + m) * 128 + l;
        float2 t;
        t.x = st[a];
        t.y = st[a + 64];
        cfma(o[m], uj, t);
      }
    }
  }

  // stores: 64 lanes x 4B contiguous = 256B (full lines) per instruction
#pragma unroll
  for (int m = 0; m < 8; m++) {
    const int off = c0 + l + ((w * 8 + m) << 19);
    __builtin_nontemporal_store(o[m].x, out + off);               // real
    __builtin_nontemporal_store(o[m].y, out + off + (1 << 24));   // imag
  }
}

extern "C" void kernel_launch(void* const* d_in, const int* in_sizes, int n_in,
                              void* d_out, int out_size, void* d_ws, size_t ws_size,
                              hipStream_t stream) {
  const float* Hre  = (const float*)d_in[0];
  const float* Him  = (const float*)d_in[1];
  const float* tevo = (const float*)d_in[2];
  const float* sre  = (const float*)d_in[3];
  const float* sim  = (const float*)d_in[4];
  float* out = (float*)d_out;
  float* uws = (float*)d_ws;  // UTOT floats = 9216 B

  compute_u_kernel<<<1, 256, 0, stream>>>(Hre, Him, tevo, uws);
  apply_gates_kernel<<<NCOL / 64, 256, 0, stream>>>(sre, sim, uws, out);
}